// Round 18
// baseline (195.532 us; speedup 1.0000x reference)
//
#include <hip/hip_runtime.h>
#include <stdint.h>

#define T_  2048
#define H_  1024
#define NH_ 16
#define HD_ 64

typedef __bf16 bf16x8 __attribute__((ext_vector_type(8)));
typedef __bf16 bf16x4 __attribute__((ext_vector_type(4)));
typedef float  f32x4  __attribute__((ext_vector_type(4)));

__device__ __forceinline__ unsigned short f2bf(float f) {
  unsigned u = __builtin_bit_cast(unsigned, f);
  u += 0x7fffu + ((u >> 16) & 1u);          // RNE
  return (unsigned short)(u >> 16);
}

__device__ __forceinline__ uint2 pack4bf(float a, float b, float c, float d) {
  bf16x4 t;                                  // native casts -> v_cvt_pk_bf16_f32
  t[0] = (__bf16)a; t[1] = (__bf16)b; t[2] = (__bf16)c; t[3] = (__bf16)d;
  return __builtin_bit_cast(uint2, t);
}

// ---------------- fused: W_eff = W + 2*B@A (y=0..2, x4-vectorized) and x->bf16 (y=3) ----------------
__global__ __launch_bounds__(256) void prep_fused(
    const float* __restrict__ Wq, const float* __restrict__ Aq, const float* __restrict__ Bq,
    const float* __restrict__ Wk, const float* __restrict__ Ak, const float* __restrict__ Bk,
    const float* __restrict__ Wv, const float* __restrict__ Av, const float* __restrict__ Bv,
    const float* __restrict__ x,
    unsigned short* __restrict__ Weff, unsigned short* __restrict__ Xb) {
  int p = blockIdx.y;
  if (p == 3) {
#pragma unroll
    for (int j = 0; j < 4; ++j) {
      int chunk = blockIdx.x * 1024 + j * 256 + threadIdx.x;
      int i = chunk * 8;
      f32x4 a = *(const f32x4*)(x + i);
      f32x4 c = *(const f32x4*)(x + i + 4);
      uint4 rv;
      rv.x = (unsigned)f2bf(a[0]) | ((unsigned)f2bf(a[1]) << 16);
      rv.y = (unsigned)f2bf(a[2]) | ((unsigned)f2bf(a[3]) << 16);
      rv.z = (unsigned)f2bf(c[0]) | ((unsigned)f2bf(c[1]) << 16);
      rv.w = (unsigned)f2bf(c[2]) | ((unsigned)f2bf(c[3]) << 16);
      *(uint4*)(Xb + i) = rv;
    }
    return;
  }
  const float* W = (p == 0) ? Wq : (p == 1) ? Wk : Wv;
  const float* A = (p == 0) ? Aq : (p == 1) ? Ak : Av;
  const float* B = (p == 0) ? Bq : (p == 1) ? Bk : Bv;
  int idx4 = (blockIdx.x * 256 + threadIdx.x) * 4;
  int o = idx4 >> 10, h0 = idx4 & 1023;
  f32x4 acc = *(const f32x4*)(W + idx4);
#pragma unroll
  for (int r = 0; r < 8; ++r) {
    float bb = 2.0f * B[o * 8 + r];                  // SCALING = 16/8 = 2
    f32x4 av = *(const f32x4*)(A + r * H_ + h0);
#pragma unroll
    for (int j = 0; j < 4; ++j) acc[j] += bb * av[j];
  }
  uint2 pk;
  pk.x = (unsigned)f2bf(acc[0]) | ((unsigned)f2bf(acc[1]) << 16);
  pk.y = (unsigned)f2bf(acc[2]) | ((unsigned)f2bf(acc[3]) << 16);
  *(uint2*)(Weff + p * (H_ * H_) + idx4) = pk;
}

// ---------------- QKV GEMM: C[m,n] = sum_k Xb[m,k] * Weff[n,k] (+bias) ----------------
// R15 config: BK=64, 2 barriers/step, XOR chunk-swizzled LDS, swapped MFMA,
// XCD-chunked swizzle, __launch_bounds__(256,3) -> 3 blocks/CU.
#define BM 128
#define BN 128
#define BK 64
__global__ __launch_bounds__(256, 3) void gemm_qkv(
    const unsigned short* __restrict__ Xb, const unsigned short* __restrict__ Weff,
    const float* __restrict__ bq, const float* __restrict__ bk, const float* __restrict__ bv,
    const float* __restrict__ mask,
    unsigned short* __restrict__ qq, unsigned short* __restrict__ kk, unsigned short* __restrict__ vP) {
  __shared__ __align__(16) unsigned short As[BM][BK];   // 16 KB
  __shared__ __align__(16) unsigned short Bs[BM][BK];   // 16 KB
  int tid = threadIdx.x;
  int bid = blockIdx.x;                          // 1536
  int xcd = bid & 7, j = bid >> 3;               // XCD-chunked swizzle
  int mt = xcd * 8 + (j & 7);                    // m-tile 0..63
  int ntile = j >> 3;                            // n-tile 0..23
  int m0 = mt * BM;
  int n0 = ntile * BN;
  int w = tid >> 6, l = tid & 63;
  int wm = w >> 1, wn = w & 1;
  int lr = l & 15, lg = l >> 4;
  const float L2E = 1.4426950408889634f;

  f32x4 acc[4][4] = {};
#pragma unroll 1
  for (int kt = 0; kt < H_ / BK; ++kt) {
    __syncthreads();
#pragma unroll
    for (int i2 = 0; i2 < 4; ++i2) {
      int c = tid + i2 * 256;                    // 1024 16B chunks per operand tile
      int row = c >> 3, slot = c & 7;
      int ks = (slot ^ (row & 7)) * 8;           // inverse-swizzled global source
      const unsigned short* ga = Xb + (size_t)(m0 + row) * H_ + kt * BK + ks;
      const unsigned short* gb = Weff + (size_t)(n0 + row) * H_ + kt * BK + ks;
      __builtin_amdgcn_global_load_lds((const __attribute__((address_space(1))) void*)ga,
                                       (__attribute__((address_space(3))) void*)(&As[0][0] + c * 8), 16, 0, 0);
      __builtin_amdgcn_global_load_lds((const __attribute__((address_space(1))) void*)gb,
                                       (__attribute__((address_space(3))) void*)(&Bs[0][0] + c * 8), 16, 0, 0);
    }
    __syncthreads();                             // drain vmcnt: tile ready
#pragma unroll
    for (int kk2 = 0; kk2 < 2; ++kk2) {          // k-slice outer: live regs stay low
      bf16x8 af[4], bf[4];
#pragma unroll
      for (int f = 0; f < 4; ++f) {
        int ra = wm * 64 + f * 16 + lr;
        int rb = wn * 64 + f * 16 + lr;
        int sa = ((kk2 << 2) | lg) ^ (ra & 7);   // swizzled read chunk
        int sb = ((kk2 << 2) | lg) ^ (rb & 7);
        af[f] = *(const bf16x8*)&As[ra][sa * 8];
        bf[f] = *(const bf16x8*)&Bs[rb][sb * 8];
      }
#pragma unroll
      for (int fm = 0; fm < 4; ++fm)
#pragma unroll
        for (int fn = 0; fn < 4; ++fn)           // swapped: lanes=tokens(m), regs=features(n)
          acc[fm][fn] = __builtin_amdgcn_mfma_f32_16x16x32_bf16(bf[fn], af[fm], acc[fm][fn], 0, 0, 0);
    }
  }

  int p = n0 >> 10;
  const float* bias = (p == 0) ? bq : (p == 1) ? bk : bv;
  const float QSCALE = 0.125f * L2E;             // softmax 1/sqrt(64) and log2-base fold
#pragma unroll
  for (int fm = 0; fm < 4; ++fm) {
    int m = m0 + wm * 64 + fm * 16 + lr;
    int bb = m >> 11, t = m & 2047;
    float expm = (p == 2) ? exp2f(mask[(size_t)bb * T_ + t] * L2E) : 1.0f;  // e^{m[k]}
#pragma unroll
    for (int fn = 0; fn < 4; ++fn) {
      int o0 = (n0 & 1023) + wn * 64 + fn * 16 + lg * 4;
      int hh = o0 >> 6, d0 = o0 & 63;
      size_t bh = (size_t)(bb * NH_ + hh);
      f32x4 b4 = *(const f32x4*)(bias + o0);
      if (p == 0) {
        *(uint2*)(qq + (bh * T_ + t) * HD_ + d0) =
          pack4bf((acc[fm][fn][0] + b4[0]) * QSCALE, (acc[fm][fn][1] + b4[1]) * QSCALE,
                  (acc[fm][fn][2] + b4[2]) * QSCALE, (acc[fm][fn][3] + b4[3]) * QSCALE);
      } else if (p == 1) {
        *(uint2*)(kk + (bh * T_ + t) * HD_ + d0) =
          pack4bf(acc[fm][fn][0] + b4[0], acc[fm][fn][1] + b4[1],
                  acc[fm][fn][2] + b4[2], acc[fm][fn][3] + b4[3]);
      } else {
        int r5 = t & 31;
        int within = ((r5 >> 2) & 3) * 8 + (r5 & 3) + ((r5 >> 4) << 2);
        size_t tbase = (size_t)(t & ~31) + within;
#pragma unroll
        for (int r = 0; r < 4; ++r)
          vP[(bh * HD_ + d0 + r) * T_ + tbase] =
            __builtin_bit_cast(unsigned short, (__bf16)((acc[fm][fn][r] + b4[r]) * expm));
      }
    }
  }
}

// ---------------- causal flash attention, LDS K/V, KVBLK=64, QBLK=32 ----------------
// Wave = 32 q-rows (two 16-row fragments u=0,1 sharing every K/V fragment):
// stage/barrier/ds-read cost per FLOP halves vs QBLK=16. Block (bh,j): two
// phases (A: q-tiles32 {4j..4j+3}, B: {60-4j..63-4j}) -> uniform 34 k-tiles
// per block; 1024 blocks = exact capacity at 4 blocks/CU (LDS 36 KB).
// R16-proven __syncthreads sync (one barrier per 64-key tile). Base-2 softmax,
// no reference; mask folded into V'; l on the MFMA pipe; zero cross-lane ops.
__global__ __launch_bounds__(256, 4) void attn_fwd(
    const unsigned short* __restrict__ qq, const unsigned short* __restrict__ kk,
    const unsigned short* __restrict__ vP, const float* __restrict__ mask,
    float* __restrict__ out) {
  __shared__ __align__(16) char lds[2][16384];   // [buf][sub0: K4K|V4K | sub1: K4K|V4K]
  __shared__ __align__(16) char cbuf[4096];      // exp(mask), permuted, all 2048 keys

  int tid = threadIdx.x;
  int w = tid >> 6, l = tid & 63;
  int bid = blockIdx.x;                          // 1024
  int bh = bid & 63;                             // bid%8==bh&7 -> XCD locality
  int j = bid >> 6;                              // 0..15
  int b = bh >> 4, h = bh & 15;
  int lr = l & 15, g8 = l >> 4;
  const float L2E = 1.4426950408889634f;
  const float NINF = -__builtin_inff();

  const unsigned short* Kp = kk + (size_t)bh * T_ * HD_;
  const unsigned short* Vp = vP + (size_t)bh * HD_ * T_;
  const float* mp = mask + b * T_;

  int krow = tid >> 3, kslot = tid & 7;
  int kgs = kslot ^ (krow & 7);
  int vsub = kgs >> 2, vslot = kgs & 3;
  int vrow = (krow << 1) | vsub;

  auto stage32 = [&](int t32, int dst, int sub) {
    int k0 = t32 * 32;
    const unsigned short* srcK = Kp + (size_t)(k0 + krow) * HD_ + kgs * 8;
    __builtin_amdgcn_global_load_lds((const __attribute__((address_space(1))) void*)srcK,
        (__attribute__((address_space(3))) void*)(&lds[dst][sub * 8192 + tid * 16]), 16, 0, 0);
    const unsigned short* srcV = Vp + (size_t)vrow * T_ + k0 + vslot * 8;
    __builtin_amdgcn_global_load_lds((const __attribute__((address_space(1))) void*)srcV,
        (__attribute__((address_space(3))) void*)(&lds[dst][sub * 8192 + 4096 + tid * 16]), 16, 0, 0);
  };
  auto stage64 = [&](int t64, int dst) { stage32(2 * t64, dst, 0); stage32(2 * t64 + 1, dst, 1); };

  int kswz = lr & 7;
  int vrd = (lr >> 1) & 7;

  int buf = 0;
  stage64(0, 0);
  {
    // build cbuf: thread t covers permuted key positions t*8..t*8+7
    int tt = tid >> 2, q8 = tid & 3;
    int base0 = tt * 32 + q8 * 4;
    f32x4 mlo = *(const f32x4*)(mp + base0);
    f32x4 mhi = *(const f32x4*)(mp + base0 + 16);
    bf16x8 cf;
#pragma unroll
    for (int r = 0; r < 4; ++r) {
      cf[r]     = (__bf16)exp2f(mlo[r] * L2E);
      cf[4 + r] = (__bf16)exp2f(mhi[r] * L2E);
    }
    *(bf16x8*)(&cbuf[tid * 16]) = cf;
  }
  __syncthreads();

#pragma unroll 1
  for (int p = 0; p < 2; ++p) {
    int jj = p ? (15 - j) : j;
    int qt32 = 4 * jj + w;                       // 32-row q-tile 0..63
    int ntmax = 2 * jj + 2;                      // block lockstep 64-key tiles
    int myNt = (qt32 >> 1) + 1;                  // my 64-key tiles
    int dsub = qt32 & 1;                         // diag in sub0 (even) or sub1 (odd)
    int t0 = qt32 * 32;
    const unsigned short* Qp = qq + ((size_t)bh * T_ + t0) * HD_;

    bf16x8 qf[2][2];
#pragma unroll
    for (int u = 0; u < 2; ++u)
#pragma unroll
      for (int hs = 0; hs < 2; ++hs)
        qf[u][hs] = *(const bf16x8*)(Qp + (u * 16 + lr) * HD_ + hs * 32 + g8 * 8);

    f32x4 accO[2][4] = {};
    f32x4 accL[2] = {};

    auto qk32 = [&](const char* kb, f32x4 (&s0)[2], f32x4 (&s1)[2]) {
#pragma unroll
      for (int hs = 0; hs < 2; ++hs) {
        int sl = ((hs << 2) | g8) ^ kswz;
        bf16x8 kc0 = *(const bf16x8*)(kb + lr * 128 + (sl << 4));
        bf16x8 kc1 = *(const bf16x8*)(kb + (16 + lr) * 128 + (sl << 4));
        __builtin_amdgcn_s_setprio(1);
#pragma unroll
        for (int u = 0; u < 2; ++u) {
          s0[u] = __builtin_amdgcn_mfma_f32_16x16x32_bf16(kc0, qf[u][hs], s0[u], 0, 0, 0);
          s1[u] = __builtin_amdgcn_mfma_f32_16x16x32_bf16(kc1, qf[u][hs], s1[u], 0, 0, 0);
        }
        __builtin_amdgcn_s_setprio(0);
      }
    };
    auto pv32 = [&](const char* kb, bf16x8 pv0, bf16x8 pv1) {
#pragma unroll
      for (int dn = 0; dn < 4; ++dn) {
        int rowp = dn * 8 + (lr >> 1);
        int sl = (((lr & 1) << 2) | g8) ^ vrd;
        bf16x8 vf = *(const bf16x8*)(kb + 4096 + rowp * 128 + (sl << 4));
        __builtin_amdgcn_s_setprio(1);
        accO[0][dn] = __builtin_amdgcn_mfma_f32_16x16x32_bf16(vf, pv0, accO[0][dn], 0, 0, 0);
        accO[1][dn] = __builtin_amdgcn_mfma_f32_16x16x32_bf16(vf, pv1, accO[1][dn], 0, 0, 0);
        __builtin_amdgcn_s_setprio(0);
      }
    };
    auto accl2 = [&](bf16x8 cf, bf16x8 pv0, bf16x8 pv1) {
      __builtin_amdgcn_s_setprio(1);
      accL[0] = __builtin_amdgcn_mfma_f32_16x16x32_bf16(cf, pv0, accL[0], 0, 0, 0);
      accL[1] = __builtin_amdgcn_mfma_f32_16x16x32_bf16(cf, pv1, accL[1], 0, 0, 0);
      __builtin_amdgcn_s_setprio(0);
    };

    // 32-key subtile, no diagonal
    auto stepN = [&](const char* kb, int k0) {
      f32x4 s0[2] = {{0.f,0.f,0.f,0.f},{0.f,0.f,0.f,0.f}};
      f32x4 s1[2] = {{0.f,0.f,0.f,0.f},{0.f,0.f,0.f,0.f}};
      qk32(kb, s0, s1);
      bf16x8 pv[2];
#pragma unroll
      for (int u = 0; u < 2; ++u)
#pragma unroll
        for (int r = 0; r < 4; ++r) {
          pv[u][r]     = (__bf16)exp2f(s0[u][r]);
          pv[u][4 + r] = (__bf16)exp2f(s1[u][r]);
        }
      bf16x8 cf = *(const bf16x8*)(&cbuf[(k0 >> 5) * 64 + g8 * 16]);
      accl2(cf, pv[0], pv[1]);
      pv32(kb, pv[0], pv[1]);
    };
    // 32-key subtile with the causal diagonal
    auto stepD = [&](const char* kb, int k0) {
      f32x4 s0[2] = {{0.f,0.f,0.f,0.f},{0.f,0.f,0.f,0.f}};
      f32x4 s1[2] = {{0.f,0.f,0.f,0.f},{0.f,0.f,0.f,0.f}};
      qk32(kb, s0, s1);
      bf16x8 pv[2];
#pragma unroll
      for (int u = 0; u < 2; ++u) {
        int qrow = t0 + u * 16 + lr;
#pragma unroll
        for (int r = 0; r < 4; ++r) {
          int ka = k0 + g8 * 4 + r;
          float a0 = (ka <= qrow)      ? s0[u][r] : NINF;
          float a1 = (ka + 16 <= qrow) ? s1[u][r] : NINF;
          pv[u][r]     = (__bf16)exp2f(a0);
          pv[u][4 + r] = (__bf16)exp2f(a1);
        }
      }
      bf16x8 cf = *(const bf16x8*)(&cbuf[(k0 >> 5) * 64 + g8 * 16]);
      accl2(cf, pv[0], pv[1]);
      pv32(kb, pv[0], pv[1]);
    };

#pragma unroll 1
    for (int ti = 0; ti < ntmax; ++ti) {
      if (ti + 1 < ntmax) stage64(ti + 1, buf ^ 1);
      else if (p == 0)    stage64(0, buf ^ 1);         // bridge into phase B
      const char* kb0 = lds[buf];
      const char* kb1 = lds[buf] + 8192;
      if (ti < myNt - 1) {
        stepN(kb0, ti * 64);
        stepN(kb1, ti * 64 + 32);
      } else if (ti == myNt - 1) {
        if (dsub == 0) {
          stepD(kb0, ti * 64);
        } else {
          stepN(kb0, ti * 64);
          stepD(kb1, ti * 64 + 32);
        }
      }
      __syncthreads();
      buf ^= 1;
    }

#pragma unroll
    for (int u = 0; u < 2; ++u) {
      float inv = 1.0f / accL[u][0];               // complete per-q sum, all lanes
      float* op = out + ((size_t)b * T_ + t0 + u * 16 + lr) * H_ + h * HD_;
#pragma unroll
      for (int dn = 0; dn < 4; ++dn) {
        f32x4 ov;
#pragma unroll
        for (int r = 0; r < 4; ++r) ov[r] = accO[u][dn][r] * inv;
        *(f32x4*)(op + dn * 16 + g8 * 4) = ov;
      }
    }
  }
}

extern "C" void kernel_launch(void* const* d_in, const int* in_sizes, int n_in,
                              void* d_out, int out_size, void* d_ws, size_t ws_size,
                              hipStream_t stream) {
  const float* x    = (const float*)d_in[0];
  const float* mask = (const float*)d_in[1];
  const float* Wq = (const float*)d_in[2];
  const float* bq = (const float*)d_in[3];
  const float* Aq = (const float*)d_in[4];
  const float* Bq = (const float*)d_in[5];
  const float* Wk = (const float*)d_in[6];
  const float* bk = (const float*)d_in[7];
  const float* Ak = (const float*)d_in[8];
  const float* Bk = (const float*)d_in[9];
  const float* Wv = (const float*)d_in[10];
  const float* bv = (const float*)d_in[11];
  const float* Av = (const float*)d_in[12];
  const float* Bv = (const float*)d_in[13];
  float* out = (float*)d_out;

  char* ws = (char*)d_ws;
  unsigned short* Xb   = (unsigned short*)(ws);                   // 16 MB  [8192][1024]
  unsigned short* Weff = (unsigned short*)(ws + (16u << 20));     //  6 MB  [3][1024][1024]
  unsigned short* qq   = (unsigned short*)(ws + (22u << 20));     // 16 MB  [4][16][2048][64]
  unsigned short* kk   = (unsigned short*)(ws + (38u << 20));     // 16 MB  [4][16][2048][64]
  unsigned short* vP   = (unsigned short*)(ws + (54u << 20));     // 16 MB  [4][16][64][2048] (permuted, mask-folded)

  prep_fused<<<dim3(1024, 4), 256, 0, stream>>>(Wq, Aq, Bq, Wk, Ak, Bk, Wv, Av, Bv, x, Weff, Xb);
  gemm_qkv<<<1536, 256, 0, stream>>>(Xb, Weff, bq, bk, bv, mask, qq, kk, vP);
  attn_fwd<<<1024, 256, 0, stream>>>(qq, kk, vP, mask, out);
}